// Round 1
// baseline (111.676 us; speedup 1.0000x reference)
//
#include <hip/hip_runtime.h>
#include <hip/hip_bf16.h>
#include <cstdint>

using u16 = unsigned short;
using u32 = unsigned int;

#define DEPTH 10
#define NF 512
#define NL 1024
#define BATCH_N 32768
#define TEMP_INV 10.0f
#define BM 64
#define BK 32

typedef float f32x4 __attribute__((ext_vector_type(4)));
typedef short s16x8 __attribute__((ext_vector_type(8)));
typedef __bf16 bf16x8 __attribute__((ext_vector_type(8)));

__device__ __forceinline__ u16 f2bf(float f) {
  u32 u = __float_as_uint(f);
  u = (u + 0x7fffu + ((u >> 16) & 1u)) >> 16;
  return (u16)u;
}

__device__ __forceinline__ void gld_lds16(const void* g, void* lds) {
  __builtin_amdgcn_global_load_lds(
      (const __attribute__((address_space(1))) void*)g,
      (__attribute__((address_space(3))) void*)lds, 16, 0, 0);
}

// ---------------- kernel 1: softmax(feature_weights) -> probs (10x512 f32)
__global__ void k_softmax(const float* __restrict__ fw, float* __restrict__ probs) {
  int w = threadIdx.x >> 6;
  int lane = threadIdx.x & 63;
  if (w >= DEPTH) return;
  const float* row = fw + w * NF;
  float v[8];
  float mx = -1e30f;
#pragma unroll
  for (int i = 0; i < 8; ++i) { v[i] = row[lane * 8 + i]; mx = fmaxf(mx, v[i]); }
#pragma unroll
  for (int s = 32; s >= 1; s >>= 1) mx = fmaxf(mx, __shfl_xor(mx, s));
  float sum = 0.f;
#pragma unroll
  for (int i = 0; i < 8; ++i) { v[i] = __expf(v[i] - mx); sum += v[i]; }
#pragma unroll
  for (int s = 32; s >= 1; s >>= 1) sum += __shfl_xor(sum, s);
  float inv = 1.0f / sum;
#pragma unroll
  for (int i = 0; i < 8; ++i) probs[w * NF + lane * 8 + i] = v[i] * inv;
}

// ---------------- kernel 2: leaf_values f32 (512x1024) -> bf16 (same layout)
__global__ void k_cvt(const float* __restrict__ lv, u16* __restrict__ lvb) {
  int i = (blockIdx.x * blockDim.x + threadIdx.x) * 8;
  float4 a = *(const float4*)(lv + i);
  float4 b = *(const float4*)(lv + i + 4);
  uint4 u;
  u.x = f2bf(a.x) | ((u32)f2bf(a.y) << 16);
  u.y = f2bf(a.z) | ((u32)f2bf(a.w) << 16);
  u.z = f2bf(b.x) | ((u32)f2bf(b.y) << 16);
  u.w = f2bf(b.z) | ((u32)f2bf(b.w) << 16);
  *(uint4*)(lvb + i) = u;
}

// ---------------- kernel 3: per-row sel -> sigmoid -> leaf_probs (bf16, into d_out bytes)
__global__ void k_rows(const float* __restrict__ x, const float* __restrict__ probs,
                       const float* __restrict__ thr, u16* lp_out) {
  __shared__ float pr[DEPTH * NF];
  for (int i = threadIdx.x; i < DEPTH * NF; i += blockDim.x) pr[i] = probs[i];
  __syncthreads();
  int lane = threadIdx.x & 63;
  int wid = blockIdx.x * (blockDim.x >> 6) + (threadIdx.x >> 6);
  int nw = gridDim.x * (blockDim.x >> 6);
  float t[DEPTH];
#pragma unroll
  for (int d = 0; d < DEPTH; ++d) t[d] = thr[d];

  for (int row = wid; row < BATCH_N; row += nw) {
    const float4* xr = (const float4*)(x + (size_t)row * NF) + lane * 2;
    float4 xa = xr[0], xb = xr[1];
    float xv[8] = {xa.x, xa.y, xa.z, xa.w, xb.x, xb.y, xb.z, xb.w};
    float p[DEPTH];
#pragma unroll
    for (int d = 0; d < DEPTH; ++d) {
      const float* prd = &pr[d * NF + lane * 8];
      float s = 0.f;
#pragma unroll
      for (int i = 0; i < 8; ++i) s += xv[i] * prd[i];
#pragma unroll
      for (int m = 32; m >= 1; m >>= 1) s += __shfl_xor(s, m);
      float z = (s - t[d]) * TEMP_INV;
      p[d] = 1.0f / (1.0f + __expf(-z));
    }
    // leaf l = lane*16 + j ; bit (9-d) of l selects p[d] vs 1-p[d]
    float pref = 1.0f;
#pragma unroll
    for (int d = 0; d < 6; ++d) {
      float pd = p[d];
      pref *= ((lane >> (5 - d)) & 1) ? pd : (1.0f - pd);
    }
    float q6a = 1.f - p[6], q6b = p[6];
    float q7a = 1.f - p[7], q7b = p[7];
    float q8a = 1.f - p[8], q8b = p[8];
    float q9a = 1.f - p[9], q9b = p[9];
    float s67[4] = {q6a * q7a, q6a * q7b, q6b * q7a, q6b * q7b}; // idx = b6<<1 | b7
    float s89[4] = {q8a * q9a, q8a * q9b, q8b * q9a, q8b * q9b}; // idx = b8<<1 | b9
    u16 o[16];
#pragma unroll
    for (int j = 0; j < 16; ++j) {
      // j = b6<<3 | b7<<2 | b8<<1 | b9
      float lpv = pref * s67[j >> 2] * s89[j & 3];
      o[j] = f2bf(lpv);
    }
    uint4* dst = (uint4*)(lp_out + (size_t)row * NL + lane * 16);
    uint4 u0, u1;
    u0.x = o[0] | ((u32)o[1] << 16);  u0.y = o[2] | ((u32)o[3] << 16);
    u0.z = o[4] | ((u32)o[5] << 16);  u0.w = o[6] | ((u32)o[7] << 16);
    u1.x = o[8] | ((u32)o[9] << 16);  u1.y = o[10] | ((u32)o[11] << 16);
    u1.z = o[12] | ((u32)o[13] << 16); u1.w = o[14] | ((u32)o[15] << 16);
    dst[0] = u0;
    dst[1] = u1;
  }
}

// ---------------- kernel 4: GEMM  C(M x 512) = lp(M x 1024, bf16) * lvb(512 x 1024, bf16)^T
// BM=64 rows per block, BN=512 (full width) so the block exclusively owns its
// M-panel: epilogue may overwrite the lp bytes (d_out aliasing) race-free.
__global__ __launch_bounds__(512) void k_gemm(const u16* lp, const u16* B, float* C) {
  __shared__ u16 As[BM * BK];   // 64 x 32
  __shared__ u16 Bs[NF * BK];   // 512 x 32
  const int tid = threadIdx.x;
  const int lane = tid & 63;
  const int w = tid >> 6;  // 0..7, wave owns cols [w*64, w*64+64)
  const int brow = blockIdx.x * BM;

  f32x4 acc[4][4];
#pragma unroll
  for (int m = 0; m < 4; ++m)
#pragma unroll
    for (int n = 0; n < 4; ++n) acc[m][n] = {0.f, 0.f, 0.f, 0.f};

  for (int kk = 0; kk < NL / BK; ++kk) {
    __syncthreads();
    if (tid < 256) {  // stage A: 64 rows x 64B
      int r = tid >> 2, c8 = tid & 3;
      gld_lds16(lp + (size_t)(brow + r) * NL + kk * BK + c8 * 8, &As[tid * 8]);
    }
#pragma unroll
    for (int it = 0; it < 4; ++it) {  // stage B: 512 rows x 64B
      int lin = it * 512 + tid;
      int r = lin >> 2, c8 = lin & 3;
      gld_lds16(B + (size_t)r * NL + kk * BK + c8 * 8, &Bs[lin * 8]);
    }
    __syncthreads();

    const int k0 = (lane >> 4) * 8;
    const int rA = lane & 15;
    bf16x8 a[4], b[4];
#pragma unroll
    for (int m = 0; m < 4; ++m)
      a[m] = __builtin_bit_cast(bf16x8, *(const s16x8*)&As[(m * 16 + rA) * BK + k0]);
#pragma unroll
    for (int n = 0; n < 4; ++n)
      b[n] = __builtin_bit_cast(bf16x8, *(const s16x8*)&Bs[(w * 64 + n * 16 + rA) * BK + k0]);
#pragma unroll
    for (int m = 0; m < 4; ++m)
#pragma unroll
      for (int n = 0; n < 4; ++n)
        acc[m][n] = __builtin_amdgcn_mfma_f32_16x16x32_bf16(a[m], b[n], acc[m][n], 0, 0, 0);
  }
  __syncthreads();

  const int c0 = lane & 15;
  const int r0 = (lane >> 4) * 4;
#pragma unroll
  for (int m = 0; m < 4; ++m)
#pragma unroll
    for (int n = 0; n < 4; ++n) {
      int col = w * 64 + n * 16 + c0;
#pragma unroll
      for (int r = 0; r < 4; ++r)
        C[(size_t)(brow + m * 16 + r0 + r) * NF + col] = acc[m][n][r];
    }
}

extern "C" void kernel_launch(void* const* d_in, const int* in_sizes, int n_in,
                              void* d_out, int out_size, void* d_ws, size_t ws_size,
                              hipStream_t stream) {
  const float* x  = (const float*)d_in[0];
  const float* fw = (const float*)d_in[1];
  const float* th = (const float*)d_in[2];
  const float* lv = (const float*)d_in[3];
  float* out = (float*)d_out;

  float* probs = (float*)d_ws;                       // 20 KB
  u16* lvb = (u16*)((char*)d_ws + DEPTH * NF * 4);   // 1 MB
  u16* lp = (u16*)d_out;                             // 64 MB, aliases out

  k_softmax<<<1, 640, 0, stream>>>(fw, probs);
  k_cvt<<<(NF * NL / 8) / 256, 256, 0, stream>>>(lv, lvb);
  k_rows<<<512, 256, 0, stream>>>(x, probs, th, lp);
  k_gemm<<<BATCH_N / BM, 512, 0, stream>>>(lp, lvb, out);
}

// Round 2
// 102.169 us; speedup vs baseline: 1.0930x; 1.0930x over previous
//
#include <hip/hip_runtime.h>
#include <hip/hip_bf16.h>
#include <cstdint>

using u16 = unsigned short;
using u32 = unsigned int;

#define DEPTH 10
#define NF 512
#define NL 1024
#define BATCH_N 32768
#define TEMP_INV 10.0f
#define GBM 128
#define GBK 64

typedef float f32x4 __attribute__((ext_vector_type(4)));
typedef short s16x8 __attribute__((ext_vector_type(8)));
typedef __bf16 bf16x8 __attribute__((ext_vector_type(8)));

__device__ __forceinline__ u16 f2bf(float f) {
  u32 u = __float_as_uint(f);
  u = (u + 0x7fffu + ((u >> 16) & 1u)) >> 16;
  return (u16)u;
}

__device__ __forceinline__ void gld_lds16(const void* g, void* lds) {
  __builtin_amdgcn_global_load_lds(
      (const __attribute__((address_space(1))) void*)g,
      (__attribute__((address_space(3))) void*)lds, 16, 0, 0);
}

// ---------------- kernel 1: softmax(feature_weights) -> probs (10x512 f32)
__global__ void k_softmax(const float* __restrict__ fw, float* __restrict__ probs) {
  int w = threadIdx.x >> 6;
  int lane = threadIdx.x & 63;
  if (w >= DEPTH) return;
  const float* row = fw + w * NF;
  float v[8];
  float mx = -1e30f;
#pragma unroll
  for (int i = 0; i < 8; ++i) { v[i] = row[lane * 8 + i]; mx = fmaxf(mx, v[i]); }
#pragma unroll
  for (int s = 32; s >= 1; s >>= 1) mx = fmaxf(mx, __shfl_xor(mx, s));
  float sum = 0.f;
#pragma unroll
  for (int i = 0; i < 8; ++i) { v[i] = __expf(v[i] - mx); sum += v[i]; }
#pragma unroll
  for (int s = 32; s >= 1; s >>= 1) sum += __shfl_xor(sum, s);
  float inv = 1.0f / sum;
#pragma unroll
  for (int i = 0; i < 8; ++i) probs[w * NF + lane * 8 + i] = v[i] * inv;
}

// ---------------- kernel 2: leaf_values f32 (512x1024) -> bf16 (same layout)
__global__ void k_cvt(const float* __restrict__ lv, u16* __restrict__ lvb) {
  int i = (blockIdx.x * blockDim.x + threadIdx.x) * 8;
  float4 a = *(const float4*)(lv + i);
  float4 b = *(const float4*)(lv + i + 4);
  uint4 u;
  u.x = f2bf(a.x) | ((u32)f2bf(a.y) << 16);
  u.y = f2bf(a.z) | ((u32)f2bf(a.w) << 16);
  u.z = f2bf(b.x) | ((u32)f2bf(b.y) << 16);
  u.w = f2bf(b.z) | ((u32)f2bf(b.w) << 16);
  *(uint4*)(lvb + i) = u;
}

// ---------------- kernel 3: per-row sel -> sigmoid -> leaf_probs (bf16, into d_out bytes)
__global__ void k_rows(const float* __restrict__ x, const float* __restrict__ probs,
                       const float* __restrict__ thr, u16* lp_out) {
  __shared__ float pr[DEPTH * NF];
  for (int i = threadIdx.x; i < DEPTH * NF; i += blockDim.x) pr[i] = probs[i];
  __syncthreads();
  int lane = threadIdx.x & 63;
  int wid = blockIdx.x * (blockDim.x >> 6) + (threadIdx.x >> 6);
  int nw = gridDim.x * (blockDim.x >> 6);
  float t[DEPTH];
#pragma unroll
  for (int d = 0; d < DEPTH; ++d) t[d] = thr[d];

  for (int row = wid; row < BATCH_N; row += nw) {
    const float4* xr = (const float4*)(x + (size_t)row * NF) + lane * 2;
    float4 xa = xr[0], xb = xr[1];
    float xv[8] = {xa.x, xa.y, xa.z, xa.w, xb.x, xb.y, xb.z, xb.w};
    float p[DEPTH];
#pragma unroll
    for (int d = 0; d < DEPTH; ++d) {
      const float* prd = &pr[d * NF + lane * 8];
      float s = 0.f;
#pragma unroll
      for (int i = 0; i < 8; ++i) s += xv[i] * prd[i];
#pragma unroll
      for (int m = 32; m >= 1; m >>= 1) s += __shfl_xor(s, m);
      float z = (s - t[d]) * TEMP_INV;
      p[d] = 1.0f / (1.0f + __expf(-z));
    }
    // leaf l = lane*16 + j ; bit (9-d) of l selects p[d] vs 1-p[d]
    float pref = 1.0f;
#pragma unroll
    for (int d = 0; d < 6; ++d) {
      float pd = p[d];
      pref *= ((lane >> (5 - d)) & 1) ? pd : (1.0f - pd);
    }
    float q6a = 1.f - p[6], q6b = p[6];
    float q7a = 1.f - p[7], q7b = p[7];
    float q8a = 1.f - p[8], q8b = p[8];
    float q9a = 1.f - p[9], q9b = p[9];
    float s67[4] = {q6a * q7a, q6a * q7b, q6b * q7a, q6b * q7b}; // idx = b6<<1 | b7
    float s89[4] = {q8a * q9a, q8a * q9b, q8b * q9a, q8b * q9b}; // idx = b8<<1 | b9
    u16 o[16];
#pragma unroll
    for (int j = 0; j < 16; ++j) {
      // j = b6<<3 | b7<<2 | b8<<1 | b9
      float lpv = pref * s67[j >> 2] * s89[j & 3];
      o[j] = f2bf(lpv);
    }
    uint4* dst = (uint4*)(lp_out + (size_t)row * NL + lane * 16);
    uint4 u0, u1;
    u0.x = o[0] | ((u32)o[1] << 16);  u0.y = o[2] | ((u32)o[3] << 16);
    u0.z = o[4] | ((u32)o[5] << 16);  u0.w = o[6] | ((u32)o[7] << 16);
    u1.x = o[8] | ((u32)o[9] << 16);  u1.y = o[10] | ((u32)o[11] << 16);
    u1.z = o[12] | ((u32)o[13] << 16); u1.w = o[14] | ((u32)o[15] << 16);
    dst[0] = u0;
    dst[1] = u1;
  }
}

// ---------------- kernel 4: GEMM  C(M x 512) = lp(M x 1024, bf16) * lvb(512 x 1024, bf16)^T
// GBM=128 rows per block, BN=512 (full width) so the block exclusively owns its
// M-panel: epilogue may overwrite the lp bytes (d_out aliasing) race-free.
// BK=64: 128B LDS row; XOR slot swizzle (slot ^= row&7) applied on BOTH the
// pre-swizzled global_load_lds source and the ds_read address -> 2-way banks.
__global__ __launch_bounds__(512, 2) void k_gemm(const u16* __restrict__ lp,
                                                 const u16* __restrict__ B,
                                                 float* __restrict__ C) {
  __shared__ u16 As[GBM * GBK];   // 16 KB
  __shared__ u16 Bs[NF * GBK];    // 64 KB
  const int tid = threadIdx.x;
  const int lane = tid & 63;
  const int w = tid >> 6;   // 0..7
  const int wm = w >> 2;    // 0..1 : 64-row group
  const int wn = w & 3;     // 0..3 : 128-col group
  const int brow = blockIdx.x * GBM;
  const u16* lpb = lp + (size_t)brow * NL;

  f32x4 acc[4][8];
#pragma unroll
  for (int m = 0; m < 4; ++m)
#pragma unroll
    for (int n = 0; n < 8; ++n) acc[m][n] = {0.f, 0.f, 0.f, 0.f};

  for (int kk = 0; kk < NL / GBK; ++kk) {
    __syncthreads();
    // stage A: 128 rows x 128 B = 1024 x 16B loads (2/thread), pre-swizzled src
#pragma unroll
    for (int it = 0; it < 2; ++it) {
      int lin = it * 512 + tid;
      int r = lin >> 3;
      int s = (lin & 7) ^ (r & 7);
      gld_lds16(lpb + (size_t)r * NL + kk * GBK + s * 8, &As[lin * 8]);
    }
    // stage B: 512 rows x 128 B = 4096 x 16B loads (8/thread)
#pragma unroll
    for (int it = 0; it < 8; ++it) {
      int lin = it * 512 + tid;
      int r = lin >> 3;
      int s = (lin & 7) ^ (r & 7);
      gld_lds16(B + (size_t)r * NL + kk * GBK + s * 8, &Bs[lin * 8]);
    }
    __syncthreads();

    const int rA = lane & 15;
    const int sBase = lane >> 4;  // 0..3
#pragma unroll
    for (int kh = 0; kh < 2; ++kh) {
      const int s = sBase + kh * 4;
      bf16x8 a[4], b[8];
#pragma unroll
      for (int m = 0; m < 4; ++m) {
        int r = wm * 64 + m * 16 + rA;
        a[m] = __builtin_bit_cast(bf16x8,
            *(const s16x8*)&As[r * GBK + ((s ^ (r & 7)) * 8)]);
      }
#pragma unroll
      for (int n = 0; n < 8; ++n) {
        int r = wn * 128 + n * 16 + rA;
        b[n] = __builtin_bit_cast(bf16x8,
            *(const s16x8*)&Bs[r * GBK + ((s ^ (r & 7)) * 8)]);
      }
#pragma unroll
      for (int m = 0; m < 4; ++m)
#pragma unroll
        for (int n = 0; n < 8; ++n)
          acc[m][n] = __builtin_amdgcn_mfma_f32_16x16x32_bf16(a[m], b[n], acc[m][n], 0, 0, 0);
    }
  }
  __syncthreads();  // drain all A reads before overwriting aliased bytes

  const int c0 = lane & 15;
  const int r0 = (lane >> 4) * 4;
#pragma unroll
  for (int m = 0; m < 4; ++m)
#pragma unroll
    for (int n = 0; n < 8; ++n) {
      int col = wn * 128 + n * 16 + c0;
#pragma unroll
      for (int r = 0; r < 4; ++r)
        C[(size_t)(brow + wm * 64 + m * 16 + r0 + r) * NF + col] = acc[m][n][r];
    }
}

extern "C" void kernel_launch(void* const* d_in, const int* in_sizes, int n_in,
                              void* d_out, int out_size, void* d_ws, size_t ws_size,
                              hipStream_t stream) {
  const float* x  = (const float*)d_in[0];
  const float* fw = (const float*)d_in[1];
  const float* th = (const float*)d_in[2];
  const float* lv = (const float*)d_in[3];
  float* out = (float*)d_out;

  float* probs = (float*)d_ws;                       // 20 KB
  u16* lvb = (u16*)((char*)d_ws + DEPTH * NF * 4);   // 1 MB
  u16* lp = (u16*)d_out;                             // 64 MB, aliases out

  k_softmax<<<1, 640, 0, stream>>>(fw, probs);
  k_cvt<<<(NF * NL / 8) / 256, 256, 0, stream>>>(lv, lvb);
  k_rows<<<2048, 256, 0, stream>>>(x, probs, th, lp);
  k_gemm<<<BATCH_N / GBM, 512, 0, stream>>>(lp, lvb, out);
}

// Round 3
// 82.395 us; speedup vs baseline: 1.3554x; 1.2400x over previous
//
#include <hip/hip_runtime.h>
#include <hip/hip_bf16.h>
#include <cstdint>

using u16 = unsigned short;
using u32 = unsigned int;

#define DEPTH 10
#define NF 512
#define NL 1024
#define BATCH_N 32768
#define TEMP_INV 10.0f
#define GBM 128
#define GBK 64

typedef float f32x4 __attribute__((ext_vector_type(4)));
typedef short s16x8 __attribute__((ext_vector_type(8)));
typedef __bf16 bf16x8 __attribute__((ext_vector_type(8)));

__device__ __forceinline__ u16 f2bf(float f) {
  u32 u = __float_as_uint(f);
  u = (u + 0x7fffu + ((u >> 16) & 1u)) >> 16;
  return (u16)u;
}

__device__ __forceinline__ void gld_lds16(const void* g, void* lds) {
  __builtin_amdgcn_global_load_lds(
      (const __attribute__((address_space(1))) void*)g,
      (__attribute__((address_space(3))) void*)lds, 16, 0, 0);
}

// ---------------- kernel 1: softmax(feature_weights) -> probs (10x512 f32)
__global__ void k_softmax(const float* __restrict__ fw, float* __restrict__ probs) {
  int w = threadIdx.x >> 6;
  int lane = threadIdx.x & 63;
  if (w >= DEPTH) return;
  const float* row = fw + w * NF;
  float v[8];
  float mx = -1e30f;
#pragma unroll
  for (int i = 0; i < 8; ++i) { v[i] = row[lane * 8 + i]; mx = fmaxf(mx, v[i]); }
#pragma unroll
  for (int s = 32; s >= 1; s >>= 1) mx = fmaxf(mx, __shfl_xor(mx, s));
  float sum = 0.f;
#pragma unroll
  for (int i = 0; i < 8; ++i) { v[i] = __expf(v[i] - mx); sum += v[i]; }
#pragma unroll
  for (int s = 32; s >= 1; s >>= 1) sum += __shfl_xor(sum, s);
  float inv = 1.0f / sum;
#pragma unroll
  for (int i = 0; i < 8; ++i) probs[w * NF + lane * 8 + i] = v[i] * inv;
}

// ---------------- kernel 2: leaf_values f32 (512x1024) -> bf16 (same layout)
__global__ void k_cvt(const float* __restrict__ lv, u16* __restrict__ lvb) {
  int i = (blockIdx.x * blockDim.x + threadIdx.x) * 8;
  float4 a = *(const float4*)(lv + i);
  float4 b = *(const float4*)(lv + i + 4);
  uint4 u;
  u.x = f2bf(a.x) | ((u32)f2bf(a.y) << 16);
  u.y = f2bf(a.z) | ((u32)f2bf(a.w) << 16);
  u.z = f2bf(b.x) | ((u32)f2bf(b.y) << 16);
  u.w = f2bf(b.z) | ((u32)f2bf(b.w) << 16);
  *(uint4*)(lvb + i) = u;
}

// ---------------- fused kernel: sel -> sigmoid -> generate A tiles -> MFMA GEMM
// Block: 128 output rows x full 512 cols. A (leaf_probs) never touches memory:
// generated per K-step into swizzled As via VALU while B loads are in flight.
#define SM_AS 0
#define SM_BS 16384
#define SM_XS 16384                 /* Xs overlays Bs (prologue only) */
#define SM_PS (16384 + 67584)       /* 128*132*4 = 67584 */
#define SM_TOTAL (16384 + 67584 + 20480)

__global__ __launch_bounds__(512, 2) void k_fused(const float* __restrict__ x,
                                                  const float* __restrict__ probs,
                                                  const float* __restrict__ thr,
                                                  const u16* __restrict__ B,
                                                  float* __restrict__ C) {
  __shared__ char smem[SM_TOTAL];
  u16* As = (u16*)(smem + SM_AS);     // [128][64] u16, slot-swizzled
  u16* Bs = (u16*)(smem + SM_BS);     // [512][64] u16, slot-swizzled
  float* Xs = (float*)(smem + SM_XS); // [128][132] f32 (prologue overlay)
  float* Ps = (float*)(smem + SM_PS); // [10][512] f32

  const int tid = threadIdx.x;
  const int lane = tid & 63;
  const int w = tid >> 6;
  const int wm = w >> 2;   // 0..1
  const int wn = w & 3;    // 0..3
  const int brow = blockIdx.x * GBM;

  const int row = tid >> 2;  // 0..127 : this thread's A-row
  const int q = tid & 3;     // leaf sub-block b4b5 / feature interleave

  // ---------- prologue: stage probs, then sel = x @ probs.T per row ----------
  for (int i = tid; i < DEPTH * NF; i += 512) Ps[i] = probs[i];

  float selacc[DEPTH];
#pragma unroll
  for (int d = 0; d < DEPTH; ++d) selacc[d] = 0.f;

  for (int ch = 0; ch < 4; ++ch) {
    __syncthreads();  // Ps ready (ch=0) / previous compute done
#pragma unroll
    for (int it = 0; it < 8; ++it) {
      int lin = it * 512 + tid;
      int r = lin >> 5, c4 = lin & 31;
      *(float4*)&Xs[r * 132 + c4 * 4] =
          *(const float4*)(x + (size_t)(brow + r) * NF + ch * 128 + c4 * 4);
    }
    __syncthreads();
#pragma unroll
    for (int i = 0; i < 32; ++i) {
      float xv = Xs[row * 132 + i * 4 + q];  // 2-way banks (free)
#pragma unroll
      for (int d = 0; d < DEPTH; ++d)
        selacc[d] += xv * Ps[d * NF + ch * 128 + i * 4 + q];  // q-distinct banks
    }
  }

  float p[DEPTH];
#pragma unroll
  for (int d = 0; d < DEPTH; ++d) {
    float s = selacc[d];
    s += __shfl_xor(s, 1);
    s += __shfl_xor(s, 2);
    float z = (s - thr[d]) * TEMP_INV;
    p[d] = 1.0f / (1.0f + __expf(-z));
  }

  // per-thread leaf factor tables: leaf = kk*64 + q*16 + jj
  // bits: b0..b3 = kk, b4b5 = q, b6..b9 = jj
  float t[16];
  {
    float f45 = ((q & 2) ? p[4] : 1.f - p[4]) * ((q & 1) ? p[5] : 1.f - p[5]);
    float a6 = 1.f - p[6], b6 = p[6];
    float a7 = 1.f - p[7], b7 = p[7];
    float a8 = 1.f - p[8], b8 = p[8];
    float a9 = 1.f - p[9], b9 = p[9];
    float s67[4] = {a6 * a7, a6 * b7, b6 * a7, b6 * b7};
    float s89[4] = {a8 * a9, a8 * b9, b8 * a9, b8 * b9};
#pragma unroll
    for (int jj = 0; jj < 16; ++jj)
      t[jj] = f45 * s67[jj >> 2] * s89[jj & 3];
  }
  const float p0a = 1.f - p[0], p0b = p[0];
  const float p1a = 1.f - p[1], p1b = p[1];
  const float p2a = 1.f - p[2], p2b = p[2];
  const float p3a = 1.f - p[3], p3b = p[3];

  f32x4 acc[4][8];
#pragma unroll
  for (int m = 0; m < 4; ++m)
#pragma unroll
    for (int n = 0; n < 8; ++n) acc[m][n] = {0.f, 0.f, 0.f, 0.f};

  // swizzled As write addresses (u16 units): slots 2q, 2q+1 of this row
  const int wsl0 = row * GBK + (((2 * q + 0) ^ (row & 7)) * 8);
  const int wsl1 = row * GBK + (((2 * q + 1) ^ (row & 7)) * 8);

  // ---------- main loop ----------
  for (int kk = 0; kk < NL / GBK; ++kk) {
    __syncthreads();  // prev iteration's LDS reads done
    // stage B slice (512 rows x 128 B), pre-swizzled source
#pragma unroll
    for (int it = 0; it < 8; ++it) {
      int lin = it * 512 + tid;
      int r = lin >> 3;
      int s = (lin & 7) ^ (r & 7);
      gld_lds16(B + (size_t)r * NL + kk * GBK + s * 8, &Bs[lin * 8]);
    }
    // generate A tile (VALU) while B loads are in flight
    float base = ((kk & 8) ? p0b : p0a) * ((kk & 4) ? p1b : p1a) *
                 ((kk & 2) ? p2b : p2a) * ((kk & 1) ? p3b : p3a);
    bf16x8 lo, hi;
#pragma unroll
    for (int jj = 0; jj < 8; ++jj) lo[jj] = (__bf16)(base * t[jj]);
#pragma unroll
    for (int jj = 0; jj < 8; ++jj) hi[jj] = (__bf16)(base * t[8 + jj]);
    *(bf16x8*)&As[wsl0] = lo;
    *(bf16x8*)&As[wsl1] = hi;
    __syncthreads();  // drains vmcnt (B) + lgkm (A writes)

    const int rA = lane & 15;
    const int sBase = lane >> 4;  // 0..3
#pragma unroll
    for (int kh = 0; kh < 2; ++kh) {
      const int s = sBase + kh * 4;
      bf16x8 a[4], b[8];
#pragma unroll
      for (int m = 0; m < 4; ++m) {
        int r = wm * 64 + m * 16 + rA;
        a[m] = __builtin_bit_cast(bf16x8,
            *(const s16x8*)&As[r * GBK + ((s ^ (r & 7)) * 8)]);
      }
#pragma unroll
      for (int n = 0; n < 8; ++n) {
        int r = wn * 128 + n * 16 + rA;
        b[n] = __builtin_bit_cast(bf16x8,
            *(const s16x8*)&Bs[r * GBK + ((s ^ (r & 7)) * 8)]);
      }
#pragma unroll
      for (int m = 0; m < 4; ++m)
#pragma unroll
        for (int n = 0; n < 8; ++n)
          acc[m][n] = __builtin_amdgcn_mfma_f32_16x16x32_bf16(a[m], b[n], acc[m][n], 0, 0, 0);
    }
  }

  // ---------- epilogue ----------
  const int c0 = lane & 15;
  const int r0 = (lane >> 4) * 4;
#pragma unroll
  for (int m = 0; m < 4; ++m)
#pragma unroll
    for (int n = 0; n < 8; ++n) {
      int col = wn * 128 + n * 16 + c0;
#pragma unroll
      for (int r = 0; r < 4; ++r)
        C[(size_t)(brow + wm * 64 + m * 16 + r0 + r) * NF + col] = acc[m][n][r];
    }
}

extern "C" void kernel_launch(void* const* d_in, const int* in_sizes, int n_in,
                              void* d_out, int out_size, void* d_ws, size_t ws_size,
                              hipStream_t stream) {
  const float* x  = (const float*)d_in[0];
  const float* fw = (const float*)d_in[1];
  const float* th = (const float*)d_in[2];
  const float* lv = (const float*)d_in[3];
  float* out = (float*)d_out;

  float* probs = (float*)d_ws;                       // 20 KB
  u16* lvb = (u16*)((char*)d_ws + DEPTH * NF * 4);   // 1 MB

  k_softmax<<<1, 640, 0, stream>>>(fw, probs);
  k_cvt<<<(NF * NL / 8) / 256, 256, 0, stream>>>(lv, lvb);
  k_fused<<<BATCH_N / GBM, 512, 0, stream>>>(x, probs, th, lvb, out);
}

// Round 4
// 70.137 us; speedup vs baseline: 1.5923x; 1.1748x over previous
//
#include <hip/hip_runtime.h>
#include <hip/hip_bf16.h>
#include <cstdint>

using u16 = unsigned short;
using u32 = unsigned int;

#define DEPTH 10
#define NF 512
#define NL 1024
#define BATCH_N 32768
#define TEMP_INV 10.0f
#define GBM 64
#define GBK 32
#define NSTEP (NL / GBK)

typedef float f32x4 __attribute__((ext_vector_type(4)));
typedef short s16x8 __attribute__((ext_vector_type(8)));
typedef __bf16 bf16x8 __attribute__((ext_vector_type(8)));
typedef __bf16 bf16x4 __attribute__((ext_vector_type(4)));

__device__ __forceinline__ u16 f2bf(float f) {
  u32 u = __float_as_uint(f);
  u = (u + 0x7fffu + ((u >> 16) & 1u)) >> 16;
  return (u16)u;
}

__device__ __forceinline__ void gld_lds16(const void* g, void* lds) {
  __builtin_amdgcn_global_load_lds(
      (const __attribute__((address_space(1))) void*)g,
      (__attribute__((address_space(3))) void*)lds, 16, 0, 0);
}

// ---------------- kernel 1: softmax(feature_weights) -> probs (10x512 f32)
__global__ void k_softmax(const float* __restrict__ fw, float* __restrict__ probs) {
  int w = threadIdx.x >> 6;
  int lane = threadIdx.x & 63;
  if (w >= DEPTH) return;
  const float* row = fw + w * NF;
  float v[8];
  float mx = -1e30f;
#pragma unroll
  for (int i = 0; i < 8; ++i) { v[i] = row[lane * 8 + i]; mx = fmaxf(mx, v[i]); }
#pragma unroll
  for (int s = 32; s >= 1; s >>= 1) mx = fmaxf(mx, __shfl_xor(mx, s));
  float sum = 0.f;
#pragma unroll
  for (int i = 0; i < 8; ++i) { v[i] = __expf(v[i] - mx); sum += v[i]; }
#pragma unroll
  for (int s = 32; s >= 1; s >>= 1) sum += __shfl_xor(sum, s);
  float inv = 1.0f / sum;
#pragma unroll
  for (int i = 0; i < 8; ++i) probs[w * NF + lane * 8 + i] = v[i] * inv;
}

// ---------------- kernel 2: leaf_values f32 (512x1024) -> bf16 (same layout)
__global__ void k_cvt(const float* __restrict__ lv, u16* __restrict__ lvb) {
  int i = (blockIdx.x * blockDim.x + threadIdx.x) * 8;
  float4 a = *(const float4*)(lv + i);
  float4 b = *(const float4*)(lv + i + 4);
  uint4 u;
  u.x = f2bf(a.x) | ((u32)f2bf(a.y) << 16);
  u.y = f2bf(a.z) | ((u32)f2bf(a.w) << 16);
  u.z = f2bf(b.x) | ((u32)f2bf(b.y) << 16);
  u.w = f2bf(b.z) | ((u32)f2bf(b.w) << 16);
  *(uint4*)(lvb + i) = u;
}

// ---------------- fused: sel -> sigmoid -> A-gen -> double-buffered MFMA GEMM
// GBM=64 rows/block, full N=512. LDS 72KB -> 2 blocks/CU. Per K-step:
// STAGE(next)+GENA(next) issued first, MFMA(cur), then ONE vmcnt(0)+barrier.
__global__ __launch_bounds__(512, 4) void k_fused(const float* __restrict__ x,
                                                  const float* __restrict__ probs,
                                                  const float* __restrict__ thr,
                                                  const u16* __restrict__ B,
                                                  float* __restrict__ C) {
  __shared__ char smem[73728];
  u16* const As = (u16*)smem;               // 2 x [64][32] u16 (4 KB each)
  u16* const Bs = (u16*)(smem + 8192);      // 2 x [512][32] u16 (32 KB each)
  float* const Ps = (float*)(smem + 40960); // overlay on Bs buf1 (20 KB), prologue only

  const int tid = threadIdx.x;
  const int lane = tid & 63;
  const int w = tid >> 6;
  const int brow = blockIdx.x * GBM;
  const int row = tid >> 3;   // 0..63 : A-row owned by this thread
  const int q = tid & 7;      // feature / leaf-chunk interleave

  // ---- prologue: stage probs into LDS, sel = x@probs.T, sigmoid, tables ----
  for (int i = tid; i < DEPTH * NF; i += 512) Ps[i] = probs[i];
  __syncthreads();

  float selacc[DEPTH];
#pragma unroll
  for (int d = 0; d < DEPTH; ++d) selacc[d] = 0.f;
  const float* xr = x + (size_t)(brow + row) * NF + q * 4;
#pragma unroll
  for (int i = 0; i < 16; ++i) {
    float4 xv = *(const float4*)(xr + i * 32);
#pragma unroll
    for (int d = 0; d < DEPTH; ++d) {
      f32x4 pv = *(const f32x4*)&Ps[d * NF + i * 32 + q * 4];
      selacc[d] += xv.x * pv[0] + xv.y * pv[1] + xv.z * pv[2] + xv.w * pv[3];
    }
  }
  float p[DEPTH];
#pragma unroll
  for (int d = 0; d < DEPTH; ++d) {
    float s = selacc[d];
    s += __shfl_xor(s, 1);
    s += __shfl_xor(s, 2);
    s += __shfl_xor(s, 4);
    p[d] = 1.0f / (1.0f + __expf(-(s - thr[d]) * TEMP_INV));
  }
  // leaf = kk*32 + j, j = q*4 + i ; bit(9-d) of leaf selects p[d] vs 1-p[d]
  // j bits: b4b3b2 = q (d=5,6,7), b1b0 = i (d=8,9); kk bits b4..b0 = d=0..4
  const float f567 = ((q & 4) ? p[5] : 1.f - p[5]) *
                     ((q & 2) ? p[6] : 1.f - p[6]) *
                     ((q & 1) ? p[7] : 1.f - p[7]);
  const float t0 = f567 * (1.f - p[8]) * (1.f - p[9]);
  const float t1 = f567 * (1.f - p[8]) * p[9];
  const float t2 = f567 * p[8] * (1.f - p[9]);
  const float t3 = f567 * p[8] * p[9];
  const float p0a = 1.f - p[0], p0b = p[0];
  const float p1a = 1.f - p[1], p1b = p[1];
  const float p2a = 1.f - p[2], p2b = p[2];
  const float p3a = 1.f - p[3], p3b = p[3];
  const float p4a = 1.f - p[4], p4b = p[4];

  // swizzled As write address (bytes): slot = j>>3 = q>>1, half = q&1
  const int awb = row * 64 + (((q >> 1) ^ (row & 3)) << 4) + ((q & 1) << 3);

  f32x4 acc[4][4];
#pragma unroll
  for (int m = 0; m < 4; ++m)
#pragma unroll
    for (int n = 0; n < 4; ++n) acc[m][n] = {0.f, 0.f, 0.f, 0.f};

  auto STAGE = [&](int step, int buf) {
#pragma unroll
    for (int it = 0; it < 4; ++it) {
      int r = it * 128 + (tid >> 2);
      int sL = tid & 3;
      const u16* src = B + (size_t)r * NL + step * GBK + ((sL ^ (r & 3)) * 8);
      gld_lds16(src, (char*)Bs + buf * 32768 + (it * 512 + tid) * 16);
    }
  };
  auto GENA = [&](int step, int buf) {
    float base = ((step & 16) ? p0b : p0a) * ((step & 8) ? p1b : p1a);
    base *= ((step & 4) ? p2b : p2a);
    base *= ((step & 2) ? p3b : p3a);
    base *= ((step & 1) ? p4b : p4a);
    bf16x4 v;
    v[0] = (__bf16)(base * t0);
    v[1] = (__bf16)(base * t1);
    v[2] = (__bf16)(base * t2);
    v[3] = (__bf16)(base * t3);
    *(bf16x4*)((char*)As + buf * 4096 + awb) = v;
  };

  // prologue stage of step 0 into buffer 0
  STAGE(0, 0);
  GENA(0, 0);
  asm volatile("s_waitcnt vmcnt(0) lgkmcnt(0)" ::: "memory");
  __builtin_amdgcn_s_barrier();

  const int rA = lane & 15;
  const int sg = lane >> 4;
  const int aoff = rA * 64 + ((sg ^ (rA & 3)) << 4);              // + m*1024 bytes
  const int boff = (w * 64 + rA) * 64 + ((sg ^ (rA & 3)) << 4);   // + n*1024 bytes

  for (int kk = 0; kk < NSTEP; ++kk) {
    const int cur = kk & 1;
    if (kk + 1 < NSTEP) {
      STAGE(kk + 1, cur ^ 1);
      GENA(kk + 1, cur ^ 1);
    }
    const char* ab = (const char*)As + cur * 4096;
    const char* bb = (const char*)Bs + cur * 32768;
    bf16x8 a0 = __builtin_bit_cast(bf16x8, *(const s16x8*)(ab + aoff));
    bf16x8 a1 = __builtin_bit_cast(bf16x8, *(const s16x8*)(ab + aoff + 1024));
    bf16x8 a2 = __builtin_bit_cast(bf16x8, *(const s16x8*)(ab + aoff + 2048));
    bf16x8 a3 = __builtin_bit_cast(bf16x8, *(const s16x8*)(ab + aoff + 3072));
#pragma unroll
    for (int n = 0; n < 4; ++n) {
      bf16x8 bn = __builtin_bit_cast(bf16x8, *(const s16x8*)(bb + boff + n * 1024));
      acc[0][n] = __builtin_amdgcn_mfma_f32_16x16x32_bf16(a0, bn, acc[0][n], 0, 0, 0);
      acc[1][n] = __builtin_amdgcn_mfma_f32_16x16x32_bf16(a1, bn, acc[1][n], 0, 0, 0);
      acc[2][n] = __builtin_amdgcn_mfma_f32_16x16x32_bf16(a2, bn, acc[2][n], 0, 0, 0);
      acc[3][n] = __builtin_amdgcn_mfma_f32_16x16x32_bf16(a3, bn, acc[3][n], 0, 0, 0);
    }
    asm volatile("s_waitcnt vmcnt(0) lgkmcnt(0)" ::: "memory");
    __builtin_amdgcn_s_barrier();
  }

  // ---- epilogue: C/D layout col=lane&15, row=(lane>>4)*4+reg ----
  const int c0 = lane & 15;
  const int r0 = (lane >> 4) * 4;
#pragma unroll
  for (int m = 0; m < 4; ++m)
#pragma unroll
    for (int n = 0; n < 4; ++n) {
      int col = w * 64 + n * 16 + c0;
#pragma unroll
      for (int r = 0; r < 4; ++r)
        C[(size_t)(brow + m * 16 + r0 + r) * NF + col] = acc[m][n][r];
    }
}

extern "C" void kernel_launch(void* const* d_in, const int* in_sizes, int n_in,
                              void* d_out, int out_size, void* d_ws, size_t ws_size,
                              hipStream_t stream) {
  const float* x  = (const float*)d_in[0];
  const float* fw = (const float*)d_in[1];
  const float* th = (const float*)d_in[2];
  const float* lv = (const float*)d_in[3];
  float* out = (float*)d_out;

  float* probs = (float*)d_ws;                       // 20 KB
  u16* lvb = (u16*)((char*)d_ws + DEPTH * NF * 4);   // 1 MB

  k_softmax<<<1, 640, 0, stream>>>(fw, probs);
  k_cvt<<<(NF * NL / 8) / 256, 256, 0, stream>>>(lv, lvb);
  k_fused<<<BATCH_N / GBM, 512, 0, stream>>>(x, probs, th, lvb, out);
}